// Round 25
// baseline (2458.413 us; speedup 1.0000x reference)
//
#include <hip/hip_runtime.h>
#include <cmath>

#define CC 21
#define CP 24                 // padded channels (48 B/px bf16, 16B-aligned)
#define HH 512
#define WW 512
#define HWSZ (HH*WW)
#define CHW (CC*HWSZ)
#define NITERS 5
#define ROWF (CC*WW)          // 10752 fp32 elems per image row in HWC (output)
#define VSTR 25               // vt LDS row stride (floats); coprime w/ 32 banks
#define NB 1024               // mega grid blocks (4/CU; capacity >=5/CU -> all resident)

struct K9 { float k[9]; };

__device__ __forceinline__ float bf16_to_f(unsigned short v) {
    union { unsigned int i; float f; } cv; cv.i = ((unsigned int)v) << 16; return cv.f;
}
__device__ __forceinline__ unsigned short f_to_bf16(float f) {
    union { float f; unsigned int i; } cv; cv.f = f;
    unsigned int b = cv.i + 0x7FFFu + ((cv.i >> 16) & 1u);   // RNE
    return (unsigned short)(b >> 16);
}
__device__ __forceinline__ float lo_bf(unsigned int u) {
    union { unsigned int i; float f; } cv; cv.i = u << 16; return cv.f;
}
__device__ __forceinline__ float hi_bf(unsigned int u) {
    union { unsigned int i; float f; } cv; cv.i = u & 0xFFFF0000u; return cv.f;
}
__device__ __forceinline__ unsigned int pack2_bf(float a, float b) {
    return (unsigned int)f_to_bf16(a) | ((unsigned int)f_to_bf16(b) << 16);
}

// sense-reversal grid barrier: bar[0]=arrive count, bar[1]=generation.
// Device-scope atomics + threadfence for cross-XCD visibility (G16).
__device__ __forceinline__ void grid_barrier(int* bar, int tx) {
    __threadfence();                              // release prior writes
    __syncthreads();
    if (tx == 0) {
        int gen = __hip_atomic_load(&bar[1], __ATOMIC_RELAXED, __HIP_MEMORY_SCOPE_AGENT);
        int prev = __hip_atomic_fetch_add(&bar[0], 1, __ATOMIC_ACQ_REL, __HIP_MEMORY_SCOPE_AGENT);
        if (prev == NB - 1) {
            __hip_atomic_store(&bar[0], 0, __ATOMIC_RELAXED, __HIP_MEMORY_SCOPE_AGENT);
            __hip_atomic_fetch_add(&bar[1], 1, __ATOMIC_RELEASE, __HIP_MEMORY_SCOPE_AGENT);
        } else {
            while (__hip_atomic_load(&bar[1], __ATOMIC_ACQUIRE, __HIP_MEMORY_SCOPE_AGENT) == gen)
                __builtin_amdgcn_s_sleep(2);
        }
    }
    __syncthreads();
    __threadfence();                              // acquire (invalidate stale caches)
}

// Merged preamble: unaries read once -> uP bf16 + softmax -> smA bf16 +
// smf/redacc slot-0 at clique-0 px; spT transpose; blocks 0-1 compute M.
__launch_bounds__(256)
__global__ void prep_kernel(const float* __restrict__ unaries,
                            const int* __restrict__ sp_map,
                            unsigned short* __restrict__ uP,
                            unsigned short* __restrict__ smA,
                            float* __restrict__ smf,
                            int* __restrict__ spT,
                            const float* __restrict__ skw,
                            const float* __restrict__ bkw,
                            const float* __restrict__ cm,
                            float* __restrict__ M,
                            const int* __restrict__ sp_indices,
                            float* __restrict__ redacc) {
    __shared__ float acc[44];
    __shared__ int anyC;
    int bid = blockIdx.x;
    int tx = threadIdx.x;
    int p = bid*256 + tx;

    if (tx < 44) acc[tx] = 0.f;
    if (tx == 0) anyC = 0;

    if (bid < 2) {
        for (int i = bid*256 + tx; i < CC*CC; i += 512) {
            int r = i / CC, k = i - r*CC;
            float a = 0.f;
            for (int j = 0; j < CC; ++j) a += cm[r*CC + j] * (skw[j*CC + k] + bkw[j*CC + k]);
            M[i] = a;
        }
    }

    int h = p >> 9, w = p & (WW - 1);
    int lab = sp_map[w*WW + h];
    spT[p] = lab;
    __syncthreads();

    const float* s = unaries + (size_t)p*CC;
    float f[CC];
    #pragma unroll
    for (int c = 0; c < CC; ++c) f[c] = s[c];

    {
        uint4 o0, o1, o2;
        o0.x = pack2_bf(f[0],f[1]);   o0.y = pack2_bf(f[2],f[3]);
        o0.z = pack2_bf(f[4],f[5]);   o0.w = pack2_bf(f[6],f[7]);
        o1.x = pack2_bf(f[8],f[9]);   o1.y = pack2_bf(f[10],f[11]);
        o1.z = pack2_bf(f[12],f[13]); o1.w = pack2_bf(f[14],f[15]);
        o2.x = pack2_bf(f[16],f[17]); o2.y = pack2_bf(f[18],f[19]);
        o2.z = pack2_bf(f[20],0.f);   o2.w = 0u;
        uint4* d = (uint4*)(uP + (size_t)p*CP);
        d[0] = o0; d[1] = o1; d[2] = o2;
    }

    float m = -1e30f;
    #pragma unroll
    for (int c = 0; c < CC; ++c) m = fmaxf(m, f[c]);
    float ssum = 0.f;
    #pragma unroll
    for (int c = 0; c < CC; ++c) { f[c] = __expf(f[c] - m); ssum += f[c]; }
    float inv = 1.f / ssum;
    #pragma unroll
    for (int c = 0; c < CC; ++c) f[c] *= inv;

    int idx = sp_indices[0];
    if (lab == idx || lab == idx + 1) {
        int mk = (lab == idx) ? 0 : 1;
        anyC = 1;
        atomicAdd(&acc[42 + mk], 1.f);
        for (int c = 0; c < CC; ++c) {
            smf[(size_t)c*HWSZ + p] = f[c];
            atomicAdd(&acc[mk*21 + c], __expf(f[c]));
        }
    }

    {
        uint4 o0, o1, o2;
        o0.x = pack2_bf(f[0],f[1]);   o0.y = pack2_bf(f[2],f[3]);
        o0.z = pack2_bf(f[4],f[5]);   o0.w = pack2_bf(f[6],f[7]);
        o1.x = pack2_bf(f[8],f[9]);   o1.y = pack2_bf(f[10],f[11]);
        o1.z = pack2_bf(f[12],f[13]); o1.w = pack2_bf(f[14],f[15]);
        o2.x = pack2_bf(f[16],f[17]); o2.y = pack2_bf(f[18],f[19]);
        o2.z = pack2_bf(f[20],0.f);   o2.w = 0u;
        uint4* d = (uint4*)(smA + (size_t)p*CP);
        d[0] = o0; d[1] = o1; d[2] = o2;
    }
    __syncthreads();
    if (anyC && tx < 44) atomicAdd(&redacc[tx], acc[tx]);
}

// Persistent mega-kernel: 5 fused CRF iterations with a manual grid barrier.
// Loop-invariant per-pixel state (uP frags, lab, norm) lives in registers.
__launch_bounds__(256, 4)
__global__ void mega_kernel(const unsigned short* smA0,
                            unsigned short* smB0,
                            float* __restrict__ smf,
                            float* __restrict__ outHWC,
                            const unsigned short* __restrict__ uP,
                            const int* __restrict__ spT,
                            const int* __restrict__ sp_indices,
                            const float* __restrict__ Mg,
                            const float* __restrict__ lwg, const float* __restrict__ hwg,
                            K9 kk, float* __restrict__ redacc, int* __restrict__ bar) {
    __shared__ __align__(16) float vt[264*VSTR];   // 26400 B (vblur tile / qlds)
    __shared__ float Bsh[42];
    __shared__ float acc[44];
    __shared__ int anyC;

    int bid = blockIdx.x;                      // 0..1023
    int xcd = bid & 7, tt = bid >> 3;
    int h  = xcd*64 + (tt >> 1);
    int w0 = (tt & 1) << 8;
    int tx = threadIdx.x;
    int w = w0 + tx;
    int p = h*WW + w;

    // ---- loop-invariant per-pixel state (registers across all 5 iters) ----
    const uint4* us = (const uint4*)(uP + (size_t)p*CP);
    uint4 q0 = us[0], q1 = us[1], q2 = us[2];
    int lab = spT[p];
    float hw0 = hwg[0], hw1 = hwg[1];
    float attc = hw0 + hw1;
    float sv = 0.f, swn = 0.f;
    #pragma unroll
    for (int t = 0; t < 9; ++t) {
        int hh = h + t - 4; if (hh >= 0 && hh < HH) sv  += kk.k[t];
        int wi = w + t - 4; if (wi >= 0 && wi < WW) swn += kk.k[t];
    }
    float invnorm = 1.f / (sv * swn);
    unsigned ur[12] = {q0.x,q0.y,q0.z,q0.w, q1.x,q1.y,q1.z,q1.w, q2.x,q2.y,q2.z,q2.w};

    const unsigned short* sIn = smA0;
    unsigned short* sOut = smB0;

    for (int it = 0; it < NITERS; ++it) {
        int last = (it == NITERS - 1);

        if (tx < 44) acc[tx] = 0.f;
        if (tx == 0) anyC = 0;
        {   // inline B from this iteration's clique partials
            const float* rc = redacc + it*64;
            if (tx < 42) {
                float s = rc[tx], n = rc[42 + tx/21];
                Bsh[tx] = logf((float)HWSZ - n + s);
            }
        }

        // ---- phase 1: BRANCH-FREE vertical blur from sIn -> vt ----
        #pragma unroll
        for (int j3 = 0; j3 < 4; ++j3) {
            int s = j3*256 + tx;
            if (s < 792) {
                int px = s / 3, sub = s - px*3;
                int gw = w0 + px - 4;
                int gwc = min(max(gw, 0), WW-1);
                float cw = (gw >= 0 && gw < WW) ? 1.f : 0.f;
                const unsigned short* colbase = sIn + (size_t)gwc*CP + sub*8;
                float a0=0,a1=0,a2=0,a3=0,a4=0,a5=0,a6=0,a7=0;
                #pragma unroll
                for (int t = 0; t < 9; ++t) {
                    int hh = h + t - 4;
                    int hhc = min(max(hh, 0), HH-1);
                    float kt = ((hh >= 0 && hh < HH) ? kk.k[t] : 0.f) * cw;
                    uint4 v = *(const uint4*)(colbase + (size_t)hhc*(WW*CP));
                    a0 += kt*lo_bf(v.x); a1 += kt*hi_bf(v.x);
                    a2 += kt*lo_bf(v.y); a3 += kt*hi_bf(v.y);
                    a4 += kt*lo_bf(v.z); a5 += kt*hi_bf(v.z);
                    a6 += kt*lo_bf(v.w); a7 += kt*hi_bf(v.w);
                }
                float* vd = vt + px*VSTR + sub*8;
                vd[0]=a0; vd[1]=a1; vd[2]=a2; vd[3]=a3;
                vd[4]=a4; vd[5]=a5; vd[6]=a6; vd[7]=a7;
            }
        }
        __syncthreads();

        // ---- phase 2: hblur from fp32 vt (stride 25: conflict-free) ----
        float b[CC];
        #pragma unroll
        for (int c = 0; c < CC; ++c) b[c] = 0.f;
        #pragma unroll
        for (int t = 0; t < 9; ++t) {
            const float* vr = vt + (tx + t)*VSTR;
            float kt = kk.k[t];
            #pragma unroll
            for (int c = 0; c < CC; ++c) b[c] += kt * vr[c];
        }

        int idxv = sp_indices[it];
        bool in1 = (lab == idxv), in2 = (lab == idxv + 1);
        bool incur = in1 | in2;

        // M-mix (branch-free); qv[21] in registers
        float qv[CC];
        float qmax = -1e30f;
        #pragma unroll
        for (int c = 0; c < CC; ++c) {
            float pw = 0.f;
            #pragma unroll
            for (int k = 0; k < CC; ++k) pw += Mg[c*CC + k] * b[k];
            float uc = (c & 1) ? hi_bf(ur[c>>1]) : lo_bf(ur[c>>1]);
            qv[c] = uc - pw*invnorm - attc;
            qmax = fmaxf(qmax, qv[c]);
        }
        // rare clique fixup (~650 px total)
        if (incur) {
            qmax = -1e30f;
            #pragma unroll
            for (int c = 0; c < CC; ++c) {
                float smv = smf[(size_t)c*HWSZ + p];
                float qm  = (smv == 0.f) ? 1.f : smv;
                float ft1 = in1 ? Bsh[c]      / qm : 0.f;
                float ft2 = in2 ? Bsh[CC + c] / qm : 0.f;
                float fta = ft1 + ft2;
                float att = lwg[c]*ft1 + hw0*(1.f - ft1) + lwg[CC + c]*fta + hw1*(1.f - fta);
                qv[c] += attc - att;
                qmax = fmaxf(qmax, qv[c]);
            }
        }

        if (!last) {
            float ssum = 0.f;
            #pragma unroll
            for (int c = 0; c < CC; ++c) {
                qv[c] = __expf(qv[c] - qmax);
                ssum += qv[c];
            }
            float inv = 1.f / ssum;
            uint4 o0, o1, o2;
            o0.x = pack2_bf(qv[0]*inv,qv[1]*inv);   o0.y = pack2_bf(qv[2]*inv,qv[3]*inv);
            o0.z = pack2_bf(qv[4]*inv,qv[5]*inv);   o0.w = pack2_bf(qv[6]*inv,qv[7]*inv);
            o1.x = pack2_bf(qv[8]*inv,qv[9]*inv);   o1.y = pack2_bf(qv[10]*inv,qv[11]*inv);
            o1.z = pack2_bf(qv[12]*inv,qv[13]*inv); o1.w = pack2_bf(qv[14]*inv,qv[15]*inv);
            o2.x = pack2_bf(qv[16]*inv,qv[17]*inv); o2.y = pack2_bf(qv[18]*inv,qv[19]*inv);
            o2.z = pack2_bf(qv[20]*inv,0.f);        o2.w = 0u;
            uint4* d = (uint4*)(sOut + (size_t)p*CP);
            d[0] = o0; d[1] = o1; d[2] = o2;

            int idx2 = sp_indices[it + 1];
            bool n1 = (lab == idx2), n2 = (lab == idx2 + 1);
            if (n1 | n2) {
                int mk = n1 ? 0 : 1;
                anyC = 1;
                atomicAdd(&acc[42 + mk], 1.f);
                for (int c = 0; c < CC; ++c) {
                    float smv = qv[c] * inv;
                    smf[(size_t)c*HWSZ + p] = smv;
                    atomicAdd(&acc[mk*21 + c], __expf(smv));
                }
            }
            __syncthreads();
            if (anyC && tx < 44) atomicAdd(&redacc[(it+1)*64 + tx], acc[tx]);

            grid_barrier(bar, tx);            // all writes visible device-wide
        } else {
            // q5 -> out (HWC fp32): qv -> vt region (reuse), transposed gather
            __syncthreads();                  // all vt reads (hblur) done
            float* qlds = vt;
            #pragma unroll
            for (int c = 0; c < CC; ++c) qlds[c*256 + tx] = qv[c];
            __syncthreads();
            float4* dst = (float4*)(outHWC + (size_t)h*ROWF + w0*CC);
            #pragma unroll
            for (int j = 0; j < 6; ++j) {
                int idx = j*256 + tx;
                if (idx < CC*256/4) {
                    int e = idx * 4;          // e = pix*CC + c
                    float4 o;
                    o.x = qlds[(e       % CC)*256 + (e       / CC)];
                    o.y = qlds[((e + 1) % CC)*256 + ((e + 1) / CC)];
                    o.z = qlds[((e + 2) % CC)*256 + ((e + 2) / CC)];
                    o.w = qlds[((e + 3) % CC)*256 + ((e + 3) / CC)];
                    dst[idx] = o;
                }
            }
        }

        const unsigned short* t1 = sIn;
        sIn = sOut;
        sOut = (unsigned short*)t1;
    }
}

extern "C" void kernel_launch(void* const* d_in, const int* in_sizes, int n_in,
                              void* d_out, int out_size, void* d_ws, size_t ws_size,
                              hipStream_t stream) {
    const float* unaries    = (const float*)d_in[0];
    // d_in[1] = rgb (unused by the reference)
    const int*   sp_map     = (const int*)d_in[2];
    const int*   sp_indices = (const int*)d_in[3];
    const float* skw        = (const float*)d_in[4];
    const float* bkw        = (const float*)d_in[5];
    const float* cm         = (const float*)d_in[6];
    const float* lw         = (const float*)d_in[7];
    const float* hwt        = (const float*)d_in[8];
    float* out = (float*)d_out;

    char* wsb = (char*)d_ws;
    unsigned short* smA = (unsigned short*)wsb;                  // HW*24 bf16
    unsigned short* smB = smA + (size_t)HWSZ*CP;                 // HW*24 bf16
    unsigned short* uP  = smB + (size_t)HWSZ*CP;                 // HW*24 bf16
    float* smf  = (float*)(uP + (size_t)HWSZ*CP);                // CHW fp32 (sparse use)
    float* M    = smf + CHW;                                     // 441
    float* redacc = M + CC*CC;                                   // 6 slots x 64
    int*   bar  = (int*)(redacc + 6*64);                         // 2 ints (+pad to 16)
    int*   spT  = (int*)(redacc + 6*64 + 16);                    // HWSZ ints

    // 9-tap normalized Gaussian, sigma=3 (fp32, matches reference)
    K9 kk;
    {
        float s = 0.f;
        for (int t = 0; t < 9; ++t) {
            float x = (float)(t - 4) / 3.0f;
            kk.k[t] = expf(-0.5f * x * x);
            s += kk.k[t];
        }
        for (int t = 0; t < 9; ++t) kk.k[t] /= s;
    }

    // zero redacc slots + barrier state (re-zeroed every call/replay)
    hipMemsetAsync(redacc, 0, (6*64 + 16)*sizeof(float), stream);
    prep_kernel<<<HWSZ/256, 256, 0, stream>>>(unaries, sp_map, uP, smA, smf, spT,
                                              skw, bkw, cm, M, sp_indices, redacc);
    mega_kernel<<<NB, 256, 0, stream>>>(smA, smB, smf, out, uP, spT,
                                        sp_indices, M, lw, hwt, kk, redacc, bar);
}

// Round 26
// 193.178 us; speedup vs baseline: 12.7262x; 12.7262x over previous
//
#include <hip/hip_runtime.h>
#include <cmath>

#define CC 21
#define CP 24                 // padded channels (48 B/px bf16, 16B-aligned)
#define HH 512
#define WW 512
#define HWSZ (HH*WW)
#define CHW (CC*HWSZ)
#define NITERS 5
#define ROWF (CC*WW)          // 10752 fp32 elems per image row in HWC (output)
#define VSTR 25               // vt LDS row stride (floats); coprime w/ 32 banks

struct K9 { float k[9]; };

__device__ __forceinline__ float bf16_to_f(unsigned short v) {
    union { unsigned int i; float f; } cv; cv.i = ((unsigned int)v) << 16; return cv.f;
}
__device__ __forceinline__ unsigned short f_to_bf16(float f) {
    union { float f; unsigned int i; } cv; cv.f = f;
    unsigned int b = cv.i + 0x7FFFu + ((cv.i >> 16) & 1u);   // RNE
    return (unsigned short)(b >> 16);
}
__device__ __forceinline__ float lo_bf(unsigned int u) {
    union { unsigned int i; float f; } cv; cv.i = u << 16; return cv.f;
}
__device__ __forceinline__ float hi_bf(unsigned int u) {
    union { unsigned int i; float f; } cv; cv.i = u & 0xFFFF0000u; return cv.f;
}
__device__ __forceinline__ unsigned int pack2_bf(float a, float b) {
    return (unsigned int)f_to_bf16(a) | ((unsigned int)f_to_bf16(b) << 16);
}

// Merged preamble: per-pixel unaries read (fp32, once) -> uP bf16 + softmax
// -> smA bf16 + smf/redacc slot-0 at clique-0 px; spT transpose; blocks 0-1
// also compute M = CM @ (SKW+BKW). One dispatch replaces four.
__launch_bounds__(256)
__global__ void prep_kernel(const float* __restrict__ unaries,
                            const int* __restrict__ sp_map,
                            unsigned short* __restrict__ uP,
                            unsigned short* __restrict__ smA,
                            float* __restrict__ smf,
                            int* __restrict__ spT,
                            const float* __restrict__ skw,
                            const float* __restrict__ bkw,
                            const float* __restrict__ cm,
                            float* __restrict__ M,
                            const int* __restrict__ sp_indices,
                            float* __restrict__ redacc) {
    __shared__ float acc[44];
    __shared__ int anyC;
    int bid = blockIdx.x;
    int tx = threadIdx.x;
    int p = bid*256 + tx;

    if (tx < 44) acc[tx] = 0.f;
    if (tx == 0) anyC = 0;

    // blocks 0-1: compute M (441 entries; ready before any fused kernel runs)
    if (bid < 2) {
        for (int i = bid*256 + tx; i < CC*CC; i += 512) {
            int r = i / CC, k = i - r*CC;
            float a = 0.f;
            for (int j = 0; j < CC; ++j) a += cm[r*CC + j] * (skw[j*CC + k] + bkw[j*CC + k]);
            M[i] = a;
        }
    }

    // transposed sp_map entry for this pixel
    int h = p >> 9, w = p & (WW - 1);
    int lab = sp_map[w*WW + h];
    spT[p] = lab;
    __syncthreads();

    // unaries (fp32, single read) -> registers
    const float* s = unaries + (size_t)p*CC;
    float f[CC];
    #pragma unroll
    for (int c = 0; c < CC; ++c) f[c] = s[c];

    // uP = bf16(u)
    {
        uint4 o0, o1, o2;
        o0.x = pack2_bf(f[0],f[1]);   o0.y = pack2_bf(f[2],f[3]);
        o0.z = pack2_bf(f[4],f[5]);   o0.w = pack2_bf(f[6],f[7]);
        o1.x = pack2_bf(f[8],f[9]);   o1.y = pack2_bf(f[10],f[11]);
        o1.z = pack2_bf(f[12],f[13]); o1.w = pack2_bf(f[14],f[15]);
        o2.x = pack2_bf(f[16],f[17]); o2.y = pack2_bf(f[18],f[19]);
        o2.z = pack2_bf(f[20],0.f);   o2.w = 0u;
        uint4* d = (uint4*)(uP + (size_t)p*CP);
        d[0] = o0; d[1] = o1; d[2] = o2;
    }

    // softmax(u) in registers
    float m = -1e30f;
    #pragma unroll
    for (int c = 0; c < CC; ++c) m = fmaxf(m, f[c]);
    float ssum = 0.f;
    #pragma unroll
    for (int c = 0; c < CC; ++c) { f[c] = __expf(f[c] - m); ssum += f[c]; }
    float inv = 1.f / ssum;
    #pragma unroll
    for (int c = 0; c < CC; ++c) f[c] *= inv;

    // clique-0 partials + sparse fp32 smf
    int idx = sp_indices[0];
    if (lab == idx || lab == idx + 1) {
        int mk = (lab == idx) ? 0 : 1;
        anyC = 1;
        atomicAdd(&acc[42 + mk], 1.f);
        for (int c = 0; c < CC; ++c) {
            smf[(size_t)c*HWSZ + p] = f[c];
            atomicAdd(&acc[mk*21 + c], __expf(f[c]));
        }
    }

    // smA = bf16(softmax)
    {
        uint4 o0, o1, o2;
        o0.x = pack2_bf(f[0],f[1]);   o0.y = pack2_bf(f[2],f[3]);
        o0.z = pack2_bf(f[4],f[5]);   o0.w = pack2_bf(f[6],f[7]);
        o1.x = pack2_bf(f[8],f[9]);   o1.y = pack2_bf(f[10],f[11]);
        o1.z = pack2_bf(f[12],f[13]); o1.w = pack2_bf(f[14],f[15]);
        o2.x = pack2_bf(f[16],f[17]); o2.y = pack2_bf(f[18],f[19]);
        o2.z = pack2_bf(f[20],0.f);   o2.w = 0u;
        uint4* d = (uint4*)(smA + (size_t)p*CP);
        d[0] = o0; d[1] = o1; d[2] = o2;
    }
    __syncthreads();
    if (anyC && tx < 44) atomicAdd(&redacc[tx], acc[tx]);
}

// FUSED per-iteration kernel (branch-free phase 1):
// vblur (792 tasks, clamped-addr/zero-weight taps -> all loads issue up front)
// -> hblur -> M-mix -> clique fixup -> softmax -> smOut + sparse smf/redacc.
__launch_bounds__(256)
__global__ void fused_kernel(const unsigned short* __restrict__ smIn,
                             unsigned short* __restrict__ smOut,
                             float* __restrict__ smf,
                             float* __restrict__ outHWC,
                             const unsigned short* __restrict__ uP,
                             const int* __restrict__ spT,
                             const int* __restrict__ sp_indices, int iter,
                             const float* __restrict__ Mg,
                             const float* __restrict__ lwg, const float* __restrict__ hwg,
                             K9 kk, float* __restrict__ redacc, int last) {
    __shared__ __align__(16) float vt[264*VSTR];   // 26400 B (vblur tile / qlds)
    __shared__ float Bsh[42];
    __shared__ float acc[44];
    __shared__ int anyC;

    int bid = blockIdx.x;                      // 0..1023
    int xcd = bid & 7, tt = bid >> 3;
    int h  = xcd*64 + (tt >> 1);
    int w0 = (tt & 1) << 8;
    int tx = threadIdx.x;

    if (tx < 44) acc[tx] = 0.f;
    if (tx == 0) anyC = 0;
    {   // inline B from accumulated partials of this iteration's clique
        const float* rc = redacc + iter*64;
        if (tx < 42) {
            float s = rc[tx], n = rc[42 + tx/21];
            Bsh[tx] = logf((float)HWSZ - n + s);
        }
    }

    int w = w0 + tx;
    int p = h*WW + w;

    // own-pixel loads issued early (latency overlapped with phase 1)
    const uint4* us = (const uint4*)(uP + (size_t)p*CP);
    uint4 q0 = us[0], q1 = us[1], q2 = us[2];
    int lab = spT[p];

    // ---- phase 1: BRANCH-FREE vertical blur from smIn -> vt ----
    #pragma unroll
    for (int j3 = 0; j3 < 4; ++j3) {
        int s = j3*256 + tx;
        if (s < 792) {
            int px = s / 3, sub = s - px*3;
            int gw = w0 + px - 4;
            int gwc = min(max(gw, 0), WW-1);
            float cw = (gw >= 0 && gw < WW) ? 1.f : 0.f;
            const unsigned short* colbase = smIn + (size_t)gwc*CP + sub*8;
            float a0=0,a1=0,a2=0,a3=0,a4=0,a5=0,a6=0,a7=0;
            #pragma unroll
            for (int t = 0; t < 9; ++t) {
                int hh = h + t - 4;
                int hhc = min(max(hh, 0), HH-1);
                float kt = ((hh >= 0 && hh < HH) ? kk.k[t] : 0.f) * cw;
                uint4 v = *(const uint4*)(colbase + (size_t)hhc*(WW*CP));
                a0 += kt*lo_bf(v.x); a1 += kt*hi_bf(v.x);
                a2 += kt*lo_bf(v.y); a3 += kt*hi_bf(v.y);
                a4 += kt*lo_bf(v.z); a5 += kt*hi_bf(v.z);
                a6 += kt*lo_bf(v.w); a7 += kt*hi_bf(v.w);
            }
            float* vd = vt + px*VSTR + sub*8;
            vd[0]=a0; vd[1]=a1; vd[2]=a2; vd[3]=a3;
            vd[4]=a4; vd[5]=a5; vd[6]=a6; vd[7]=a7;
        }
    }
    __syncthreads();

    // ---- phase 2: hblur from fp32 vt (stride 25: conflict-free) ----
    float b[CC];
    #pragma unroll
    for (int c = 0; c < CC; ++c) b[c] = 0.f;
    #pragma unroll
    for (int t = 0; t < 9; ++t) {
        const float* vr = vt + (tx + t)*VSTR;
        float kt = kk.k[t];
        #pragma unroll
        for (int c = 0; c < CC; ++c) b[c] += kt * vr[c];
    }

    // separable norm = s(h)*s(w)
    float sv = 0.f, swn = 0.f;
    #pragma unroll
    for (int t = 0; t < 9; ++t) {
        int hh = h + t - 4; if (hh >= 0 && hh < HH) sv  += kk.k[t];
        int wi = w + t - 4; if (wi >= 0 && wi < WW) swn += kk.k[t];
    }
    float invnorm = 1.f / (sv * swn);

    unsigned ur[12] = {q0.x,q0.y,q0.z,q0.w, q1.x,q1.y,q1.z,q1.w, q2.x,q2.y,q2.z,q2.w};

    int idxv = sp_indices[iter];
    bool in1 = (lab == idxv), in2 = (lab == idxv + 1);
    bool incur = in1 | in2;
    float hw0 = hwg[0], hw1 = hwg[1];
    float attc = hw0 + hw1;

    // M-mix (branch-free); qv[21] in registers
    float qv[CC];
    float qmax = -1e30f;
    #pragma unroll
    for (int c = 0; c < CC; ++c) {
        float pw = 0.f;
        #pragma unroll
        for (int k = 0; k < CC; ++k) pw += Mg[c*CC + k] * b[k];
        float uc = (c & 1) ? hi_bf(ur[c>>1]) : lo_bf(ur[c>>1]);
        qv[c] = uc - pw*invnorm - attc;
        qmax = fmaxf(qmax, qv[c]);
    }
    // rare clique fixup (~650 px total)
    if (incur) {
        qmax = -1e30f;
        #pragma unroll
        for (int c = 0; c < CC; ++c) {
            float smv = smf[(size_t)c*HWSZ + p];
            float qm  = (smv == 0.f) ? 1.f : smv;
            float ft1 = in1 ? Bsh[c]      / qm : 0.f;
            float ft2 = in2 ? Bsh[CC + c] / qm : 0.f;
            float fta = ft1 + ft2;
            float att = lwg[c]*ft1 + hw0*(1.f - ft1) + lwg[CC + c]*fta + hw1*(1.f - fta);
            qv[c] += attc - att;
            qmax = fmaxf(qmax, qv[c]);
        }
    }

    if (!last) {
        // softmax in registers; store smOut straight from registers (3 uint4)
        float ssum = 0.f;
        #pragma unroll
        for (int c = 0; c < CC; ++c) {
            qv[c] = __expf(qv[c] - qmax);
            ssum += qv[c];
        }
        float inv = 1.f / ssum;
        uint4 o0, o1, o2;
        o0.x = pack2_bf(qv[0]*inv,qv[1]*inv);   o0.y = pack2_bf(qv[2]*inv,qv[3]*inv);
        o0.z = pack2_bf(qv[4]*inv,qv[5]*inv);   o0.w = pack2_bf(qv[6]*inv,qv[7]*inv);
        o1.x = pack2_bf(qv[8]*inv,qv[9]*inv);   o1.y = pack2_bf(qv[10]*inv,qv[11]*inv);
        o1.z = pack2_bf(qv[12]*inv,qv[13]*inv); o1.w = pack2_bf(qv[14]*inv,qv[15]*inv);
        o2.x = pack2_bf(qv[16]*inv,qv[17]*inv); o2.y = pack2_bf(qv[18]*inv,qv[19]*inv);
        o2.z = pack2_bf(qv[20]*inv,0.f);        o2.w = 0u;
        uint4* d = (uint4*)(smOut + (size_t)p*CP);
        d[0] = o0; d[1] = o1; d[2] = o2;

        int idx2 = sp_indices[iter + 1];
        bool n1 = (lab == idx2), n2 = (lab == idx2 + 1);
        if (n1 | n2) {
            int mk = n1 ? 0 : 1;
            anyC = 1;
            atomicAdd(&acc[42 + mk], 1.f);
            for (int c = 0; c < CC; ++c) {
                float smv = qv[c] * inv;
                smf[(size_t)c*HWSZ + p] = smv;
                atomicAdd(&acc[mk*21 + c], __expf(smv));
            }
        }
        __syncthreads();
        if (anyC && tx < 44) atomicAdd(&redacc[(iter+1)*64 + tx], acc[tx]);
    } else {
        // q5 -> out (HWC fp32, 21ch): qv -> vt region (reuse), transposed gather
        __syncthreads();                      // all vt reads (hblur) done
        float* qlds = vt;                     // [CC][256] fp32 = 21504 B fits
        #pragma unroll
        for (int c = 0; c < CC; ++c) qlds[c*256 + tx] = qv[c];
        __syncthreads();
        float4* dst = (float4*)(outHWC + (size_t)h*ROWF + w0*CC);
        #pragma unroll
        for (int j = 0; j < 6; ++j) {
            int idx = j*256 + tx;
            if (idx < CC*256/4) {
                int e = idx * 4;              // e = pix*CC + c
                float4 o;
                o.x = qlds[(e       % CC)*256 + (e       / CC)];
                o.y = qlds[((e + 1) % CC)*256 + ((e + 1) / CC)];
                o.z = qlds[((e + 2) % CC)*256 + ((e + 2) / CC)];
                o.w = qlds[((e + 3) % CC)*256 + ((e + 3) / CC)];
                dst[idx] = o;
            }
        }
    }
}

extern "C" void kernel_launch(void* const* d_in, const int* in_sizes, int n_in,
                              void* d_out, int out_size, void* d_ws, size_t ws_size,
                              hipStream_t stream) {
    const float* unaries    = (const float*)d_in[0];
    // d_in[1] = rgb (unused by the reference)
    const int*   sp_map     = (const int*)d_in[2];
    const int*   sp_indices = (const int*)d_in[3];
    const float* skw        = (const float*)d_in[4];
    const float* bkw        = (const float*)d_in[5];
    const float* cm         = (const float*)d_in[6];
    const float* lw         = (const float*)d_in[7];
    const float* hwt        = (const float*)d_in[8];
    float* out = (float*)d_out;

    char* wsb = (char*)d_ws;
    unsigned short* smA = (unsigned short*)wsb;                  // HW*24 bf16
    unsigned short* smB = smA + (size_t)HWSZ*CP;                 // HW*24 bf16
    unsigned short* uP  = smB + (size_t)HWSZ*CP;                 // HW*24 bf16
    float* smf  = (float*)(uP + (size_t)HWSZ*CP);                // CHW fp32 (sparse use)
    float* M    = smf + CHW;                                     // 441
    float* redacc = M + CC*CC;                                   // 6 slots x 64
    int*   spT  = (int*)(redacc + 6*64);                         // HWSZ ints

    // 9-tap normalized Gaussian, sigma=3 (fp32, matches reference)
    K9 kk;
    {
        float s = 0.f;
        for (int t = 0; t < 9; ++t) {
            float x = (float)(t - 4) / 3.0f;
            kk.k[t] = expf(-0.5f * x * x);
            s += kk.k[t];
        }
        for (int t = 0; t < 9; ++t) kk.k[t] /= s;
    }

    hipMemsetAsync(redacc, 0, 6*64*sizeof(float), stream);
    prep_kernel<<<HWSZ/256, 256, 0, stream>>>(unaries, sp_map, uP, smA, smf, spT,
                                              skw, bkw, cm, M, sp_indices, redacc);

    unsigned short* sIn = smA;
    unsigned short* sOut = smB;
    for (int it = 0; it < NITERS; ++it) {
        int last = (it == NITERS - 1);
        fused_kernel<<<1024, 256, 0, stream>>>(sIn, sOut, smf, out, uP, spT,
                                               sp_indices, it, M, lw, hwt,
                                               kk, redacc, last);
        unsigned short* t_ = sIn; sIn = sOut; sOut = t_;
    }
}